// Round 2
// baseline (15221.739 us; speedup 1.0000x reference)
//
#include <hip/hip_runtime.h>
#include <hip/hip_bf16.h>

// ---------------------------------------------------------------------------
// Strict f64 squared distance matching numpy float64:
//   d = ((dx*dx + dy*dy) + dz*dz), every op individually rounded, no FMA.
// Coords are exact f32 values upcast to f64 (exact).
// ---------------------------------------------------------------------------
__device__ __forceinline__ double dist2d(float x, float y, float z,
                                         double px, double py, double pz) {
    double dx = __dsub_rn((double)x, px);
    double dy = __dsub_rn((double)y, py);
    double dz = __dsub_rn((double)z, pz);
    double a  = __dmul_rn(dx, dx);
    double b  = __dmul_rn(dy, dy);
    double c  = __dmul_rn(dz, dz);
    return __dadd_rn(__dadd_rn(a, b), c);
}

__device__ __forceinline__ double shfl_xor_f64(double v, int m) {
    long long bits = __double_as_longlong(v);
    int lo = __shfl_xor((int)(bits & 0xFFFFFFFFLL), m, 64);
    int hi = __shfl_xor((int)(((unsigned long long)bits) >> 32), m, 64);
    return __longlong_as_double(((long long)(unsigned)hi << 32) | (unsigned)lo);
}

__device__ __forceinline__ double shfl0_f64(double v) {
    long long bits = __double_as_longlong(v);
    int lo = __shfl((int)(bits & 0xFFFFFFFFLL), 0, 64);
    int hi = __shfl((int)(((unsigned long long)bits) >> 32), 0, 64);
    return __longlong_as_double(((long long)(unsigned)hi << 32) | (unsigned)lo);
}

// ---------------------------------------------------------------------------
// FPS: one block (1024 threads) per batch. Point p = j*1024 + tid, j<PPT.
// Coords f32 in registers (exact); running min-dists f64 (bit-matches a
// numpy float64 reference). Argmax carries (dist, idx) with lexicographic
// compare: dist desc, idx asc (numpy first-occurrence tie-break).
// One __syncthreads per iteration (double-buffered wave-partial LDS).
// ---------------------------------------------------------------------------
template <int PPT>
__global__ __launch_bounds__(1024) void fps_kernel(
    const float* __restrict__ pts,  // [B][n_in][stride], xyz at channels 0..2
    int stride, int n_in, int npoints,
    int* __restrict__ idx_out)      // [B][npoints]
{
    const int batch = blockIdx.x;
    const int tid   = threadIdx.x;
    const int lane  = tid & 63;
    const int wv    = tid >> 6;

    const float* base = pts + (size_t)batch * n_in * stride;
    int* iout = idx_out + (size_t)batch * npoints;

    __shared__ double pd[2][16];
    __shared__ int    pi[2][16];

    float  mx[PPT], my[PPT], mz[PPT];
    double mind[PPT];

#pragma unroll
    for (int j = 0; j < PPT; ++j) {
        int p = j * 1024 + tid;
        const float* r = base + (size_t)p * stride;
        mx[j] = r[0]; my[j] = r[1]; mz[j] = r[2];
    }

    // first selected point is index 0
    double px = (double)base[0], py = (double)base[1], pz = (double)base[2];
    if (tid == 0) iout[0] = 0;

#pragma unroll
    for (int j = 0; j < PPT; ++j)
        mind[j] = dist2d(mx[j], my[j], mz[j], px, py, pz);

    for (int i = 1; i < npoints; ++i) {
        // local argmax over this thread's PPT points (ascending index order,
        // strict > keeps the lowest index on ties)
        double bv = mind[0];
        int    bi = tid;
#pragma unroll
        for (int j = 1; j < PPT; ++j) {
            if (mind[j] > bv) { bv = mind[j]; bi = j * 1024 + tid; }
        }

        // wave-level (dist,idx) max reduction, tie -> smaller idx
#pragma unroll
        for (int m = 32; m >= 1; m >>= 1) {
            double ov = shfl_xor_f64(bv, m);
            int    oi = __shfl_xor(bi, m, 64);
            if (ov > bv || (ov == bv && oi < bi)) { bv = ov; bi = oi; }
        }
        if (lane == 0) { pd[i & 1][wv] = bv; pi[i & 1][wv] = bi; }
        __syncthreads();

        // every wave redundantly reduces the 16 wave partials
        double v2 = (lane < 16) ? pd[i & 1][lane] : -1.0;
        int    i2 = (lane < 16) ? pi[i & 1][lane] : 0x7FFFFFFF;
#pragma unroll
        for (int m = 8; m >= 1; m >>= 1) {
            double ov = shfl_xor_f64(v2, m);
            int    oi = __shfl_xor(i2, m, 64);
            if (ov > v2 || (ov == v2 && oi < i2)) { v2 = ov; i2 = oi; }
        }
        int best = __shfl(i2, 0, 64);
        if (tid == 0) iout[i] = best;

        // broadcast load of the winner's coords (same address across lanes)
        const float* rb = base + (size_t)best * stride;
        double qx = (double)rb[0], qy = (double)rb[1], qz = (double)rb[2];

#pragma unroll
        for (int j = 0; j < PPT; ++j) {
            double d = dist2d(mx[j], my[j], mz[j], qx, qy, qz);
            mind[j] = fmin(mind[j], d);
        }
    }
}

// ---------------------------------------------------------------------------
// Gather + 2-layer pointwise MLP + xyz/feat concat, one kernel per level.
// Block: 256 threads = P points x F channels. LDS stages the gathered row
// (xs) and hidden activations (h); all LDS reads are same-address broadcasts
// within a point group -> conflict-free.
// out[., c] = c < 3 ? gathered_xyz[c] : feat[c]
// ---------------------------------------------------------------------------
template <int CIN, int F, bool REPEAT>
__global__ __launch_bounds__(256) void mlp_kernel(
    const float* __restrict__ pts, int stride, int n_in,
    const int* __restrict__ idx,
    const float* __restrict__ w1, const float* __restrict__ b1,
    const float* __restrict__ w2, const float* __restrict__ b2,
    float* __restrict__ out, int np)
{
    constexpr int P    = 256 / F;
    constexpr int CINS = REPEAT ? (CIN / 2) : CIN;  // stored input channels
    constexpr int LOGF = (F == 16) ? 4 : (F == 32) ? 5 : (F == 64) ? 6 : 7;

    __shared__ float xs[P][CINS];
    __shared__ float h[P][F];

    const int tid = threadIdx.x;
    const int pl  = tid >> LOGF;       // point within block
    const int c   = tid & (F - 1);     // output channel
    const int b   = blockIdx.y;
    const int pid = blockIdx.x * P + pl;

    const int id = idx[(size_t)b * np + pid];
    const float* row = pts + ((size_t)b * n_in + id) * stride;

    if (c < CINS) xs[pl][c] = row[c];
    __syncthreads();

    // h = relu(x @ w1 + b1)
    float acc = b1[c];
#pragma unroll
    for (int k = 0; k < CIN; ++k) {
        const int xk = REPEAT ? (k % 3) : k;
        acc = fmaf(xs[pl][xk], w1[k * F + c], acc);
    }
    h[pl][c] = fmaxf(acc, 0.0f);
    __syncthreads();

    // feat = h @ w2 + b2
    float acc2 = b2[c];
#pragma unroll
    for (int f = 0; f < F; ++f)
        acc2 = fmaf(h[pl][f], w2[f * F + c], acc2);

    float res = (c < 3) ? xs[pl][c] : acc2;
    out[((size_t)b * np + pid) * (size_t)F + c] = res;
}

// ---------------------------------------------------------------------------
// Launch
// ---------------------------------------------------------------------------
extern "C" void kernel_launch(void* const* d_in, const int* in_sizes, int n_in_cnt,
                              void* d_out, int out_size, void* d_ws, size_t ws_size,
                              hipStream_t stream) {
    const float* scene = (const float*)d_in[0];
    const float* w1_1 = (const float*)d_in[1];
    const float* b1_1 = (const float*)d_in[2];
    const float* w2_1 = (const float*)d_in[3];
    const float* b2_1 = (const float*)d_in[4];
    const float* w1_2 = (const float*)d_in[5];
    const float* b1_2 = (const float*)d_in[6];
    const float* w2_2 = (const float*)d_in[7];
    const float* b2_2 = (const float*)d_in[8];
    const float* w1_3 = (const float*)d_in[9];
    const float* b1_3 = (const float*)d_in[10];
    const float* w2_3 = (const float*)d_in[11];
    const float* b2_3 = (const float*)d_in[12];
    const float* w1_4 = (const float*)d_in[13];
    const float* b1_4 = (const float*)d_in[14];
    const float* w2_4 = (const float*)d_in[15];
    const float* b2_4 = (const float*)d_in[16];

    float* out  = (float*)d_out;
    float* out1 = out;                 // [8][4096][16]
    float* out2 = out + 524288;        // [8][2048][32]
    float* out3 = out + 1048576;       // [8][1024][64]
    float* out4 = out + 1572864;       // [8][512][128]

    int* idx1 = (int*)d_ws;            // 8*4096
    int* idx2 = idx1 + 8 * 4096;       // 8*2048
    int* idx3 = idx2 + 8 * 2048;       // 8*1024
    int* idx4 = idx3 + 8 * 1024;       // 8*512

    const int B = 8;

    // Level 1: N=8192 -> 4096, cin=6 (repeat), F=16
    fps_kernel<8><<<B, 1024, 0, stream>>>(scene, 3, 8192, 4096, idx1);
    mlp_kernel<6, 16, true><<<dim3(256, B), 256, 0, stream>>>(
        scene, 3, 8192, idx1, w1_1, b1_1, w2_1, b2_1, out1, 4096);

    // Level 2: 4096 -> 2048, cin=16, F=32
    fps_kernel<4><<<B, 1024, 0, stream>>>(out1, 16, 4096, 2048, idx2);
    mlp_kernel<16, 32, false><<<dim3(256, B), 256, 0, stream>>>(
        out1, 16, 4096, idx2, w1_2, b1_2, w2_2, b2_2, out2, 2048);

    // Level 3: 2048 -> 1024, cin=32, F=64
    fps_kernel<2><<<B, 1024, 0, stream>>>(out2, 32, 2048, 1024, idx3);
    mlp_kernel<32, 64, false><<<dim3(256, B), 256, 0, stream>>>(
        out2, 32, 2048, idx3, w1_3, b1_3, w2_3, b2_3, out3, 1024);

    // Level 4: 1024 -> 512, cin=64, F=128
    fps_kernel<1><<<B, 1024, 0, stream>>>(out3, 64, 1024, 512, idx4);
    mlp_kernel<64, 128, false><<<dim3(256, B), 256, 0, stream>>>(
        out3, 64, 1024, idx4, w1_4, b1_4, w2_4, b2_4, out4, 512);
}

// Round 3
// 11946.967 us; speedup vs baseline: 1.2741x; 1.2741x over previous
//
#include <hip/hip_runtime.h>
#include <hip/hip_bf16.h>

// ---------------------------------------------------------------------------
// Strict f64 squared distance matching numpy float64:
//   d = ((dx*dx + dy*dy) + dz*dz), every op individually rounded, no FMA.
// Coords are exact f32 values upcast to f64 (exact).
// ---------------------------------------------------------------------------
__device__ __forceinline__ double dist2d(float x, float y, float z,
                                         double px, double py, double pz) {
    double dx = __dsub_rn((double)x, px);
    double dy = __dsub_rn((double)y, py);
    double dz = __dsub_rn((double)z, pz);
    double a  = __dmul_rn(dx, dx);
    double b  = __dmul_rn(dy, dy);
    double c  = __dmul_rn(dz, dz);
    return __dadd_rn(__dadd_rn(a, b), c);
}

__device__ __forceinline__ double shfl_xor_f64(double v, int m) {
    long long bits = __double_as_longlong(v);
    int lo = __shfl_xor((int)(bits & 0xFFFFFFFFLL), m, 64);
    int hi = __shfl_xor((int)(((unsigned long long)bits) >> 32), m, 64);
    return __longlong_as_double(((long long)(unsigned)hi << 32) | (unsigned)lo);
}

// ---------------------------------------------------------------------------
// FPS: one block (256 threads = 4 waves) per batch. Point p = j*256 + tid.
// Coords f32 in registers (exact); running min-dists f64 (bit-matches the
// numpy float64 reference). Argmax carries (dist, idx) with lexicographic
// compare: dist desc, idx asc (numpy first-occurrence tie-break).
// 4 waves -> 4x less shuffle/DS-pipe traffic per iteration than the 1024-
// thread version; one __syncthreads per iteration (double-buffered partials).
// ---------------------------------------------------------------------------
template <int PPT>
__global__ __launch_bounds__(256, 1) void fps_kernel(
    const float* __restrict__ pts,  // [B][n_in][stride], xyz at channels 0..2
    int stride, int n_in, int npoints,
    int* __restrict__ idx_out)      // [B][npoints]
{
    const int batch = blockIdx.x;
    const int tid   = threadIdx.x;
    const int lane  = tid & 63;
    const int wv    = tid >> 6;

    const float* base = pts + (size_t)batch * n_in * stride;
    int* iout = idx_out + (size_t)batch * npoints;

    __shared__ double pd[2][4];
    __shared__ int    pi[2][4];

    float  mx[PPT], my[PPT], mz[PPT];
    double mind[PPT];

#pragma unroll
    for (int j = 0; j < PPT; ++j) {
        int p = j * 256 + tid;
        const float* r = base + (size_t)p * stride;
        mx[j] = r[0]; my[j] = r[1]; mz[j] = r[2];
    }

    // first selected point is index 0
    double px = (double)base[0], py = (double)base[1], pz = (double)base[2];
    if (tid == 0) iout[0] = 0;

#pragma unroll
    for (int j = 0; j < PPT; ++j)
        mind[j] = dist2d(mx[j], my[j], mz[j], px, py, pz);

    for (int i = 1; i < npoints; ++i) {
        // local argmax over this thread's PPT points (ascending index order,
        // strict > keeps the lowest index on ties)
        double bv = mind[0];
        int    bi = tid;
#pragma unroll
        for (int j = 1; j < PPT; ++j) {
            if (mind[j] > bv) { bv = mind[j]; bi = j * 256 + tid; }
        }

        // wave-level (dist,idx) max reduction, tie -> smaller idx
#pragma unroll
        for (int m = 32; m >= 1; m >>= 1) {
            double ov = shfl_xor_f64(bv, m);
            int    oi = __shfl_xor(bi, m, 64);
            if (ov > bv || (ov == bv && oi < bi)) { bv = ov; bi = oi; }
        }
        if (lane == 0) { pd[i & 1][wv] = bv; pi[i & 1][wv] = bi; }
        __syncthreads();

        // every wave redundantly reduces the 4 wave partials (no 2nd barrier)
        double v2 = (lane < 4) ? pd[i & 1][lane] : -1.0;
        int    i2 = (lane < 4) ? pi[i & 1][lane] : 0x7FFFFFFF;
#pragma unroll
        for (int m = 2; m >= 1; m >>= 1) {
            double ov = shfl_xor_f64(v2, m);
            int    oi = __shfl_xor(i2, m, 64);
            if (ov > v2 || (ov == v2 && oi < i2)) { v2 = ov; i2 = oi; }
        }
        int best = __shfl(i2, 0, 64);
        if (tid == 0) iout[i] = best;

        // broadcast load of the winner's coords (same address across lanes,
        // L2-hot single transaction)
        const float* rb = base + (size_t)best * stride;
        double qx = (double)rb[0], qy = (double)rb[1], qz = (double)rb[2];

#pragma unroll
        for (int j = 0; j < PPT; ++j) {
            double d = dist2d(mx[j], my[j], mz[j], qx, qy, qz);
            mind[j] = fmin(mind[j], d);
        }
    }
}

// ---------------------------------------------------------------------------
// Gather + 2-layer pointwise MLP + xyz/feat concat, one kernel per level.
// Block: 256 threads = P points x F channels. LDS stages the gathered row
// (xs) and hidden activations (h); all LDS reads are same-address broadcasts
// within a point group -> conflict-free.
// out[., c] = c < 3 ? gathered_xyz[c] : feat[c]
// ---------------------------------------------------------------------------
template <int CIN, int F, bool REPEAT>
__global__ __launch_bounds__(256) void mlp_kernel(
    const float* __restrict__ pts, int stride, int n_in,
    const int* __restrict__ idx,
    const float* __restrict__ w1, const float* __restrict__ b1,
    const float* __restrict__ w2, const float* __restrict__ b2,
    float* __restrict__ out, int np)
{
    constexpr int P    = 256 / F;
    constexpr int CINS = REPEAT ? (CIN / 2) : CIN;  // stored input channels
    constexpr int LOGF = (F == 16) ? 4 : (F == 32) ? 5 : (F == 64) ? 6 : 7;

    __shared__ float xs[P][CINS];
    __shared__ float h[P][F];

    const int tid = threadIdx.x;
    const int pl  = tid >> LOGF;       // point within block
    const int c   = tid & (F - 1);     // output channel
    const int b   = blockIdx.y;
    const int pid = blockIdx.x * P + pl;

    const int id = idx[(size_t)b * np + pid];
    const float* row = pts + ((size_t)b * n_in + id) * stride;

    if (c < CINS) xs[pl][c] = row[c];
    __syncthreads();

    // h = relu(x @ w1 + b1)
    float acc = b1[c];
#pragma unroll
    for (int k = 0; k < CIN; ++k) {
        const int xk = REPEAT ? (k % 3) : k;
        acc = fmaf(xs[pl][xk], w1[k * F + c], acc);
    }
    h[pl][c] = fmaxf(acc, 0.0f);
    __syncthreads();

    // feat = h @ w2 + b2
    float acc2 = b2[c];
#pragma unroll
    for (int f = 0; f < F; ++f)
        acc2 = fmaf(h[pl][f], w2[f * F + c], acc2);

    float res = (c < 3) ? xs[pl][c] : acc2;
    out[((size_t)b * np + pid) * (size_t)F + c] = res;
}

// ---------------------------------------------------------------------------
// Launch
// ---------------------------------------------------------------------------
extern "C" void kernel_launch(void* const* d_in, const int* in_sizes, int n_in_cnt,
                              void* d_out, int out_size, void* d_ws, size_t ws_size,
                              hipStream_t stream) {
    const float* scene = (const float*)d_in[0];
    const float* w1_1 = (const float*)d_in[1];
    const float* b1_1 = (const float*)d_in[2];
    const float* w2_1 = (const float*)d_in[3];
    const float* b2_1 = (const float*)d_in[4];
    const float* w1_2 = (const float*)d_in[5];
    const float* b1_2 = (const float*)d_in[6];
    const float* w2_2 = (const float*)d_in[7];
    const float* b2_2 = (const float*)d_in[8];
    const float* w1_3 = (const float*)d_in[9];
    const float* b1_3 = (const float*)d_in[10];
    const float* w2_3 = (const float*)d_in[11];
    const float* b2_3 = (const float*)d_in[12];
    const float* w1_4 = (const float*)d_in[13];
    const float* b1_4 = (const float*)d_in[14];
    const float* w2_4 = (const float*)d_in[15];
    const float* b2_4 = (const float*)d_in[16];

    float* out  = (float*)d_out;
    float* out1 = out;                 // [8][4096][16]
    float* out2 = out + 524288;        // [8][2048][32]
    float* out3 = out + 1048576;       // [8][1024][64]
    float* out4 = out + 1572864;       // [8][512][128]

    int* idx1 = (int*)d_ws;            // 8*4096
    int* idx2 = idx1 + 8 * 4096;       // 8*2048
    int* idx3 = idx2 + 8 * 2048;       // 8*1024
    int* idx4 = idx3 + 8 * 1024;       // 8*512

    const int B = 8;

    // Level 1: N=8192 -> 4096, cin=6 (repeat), F=16
    fps_kernel<32><<<B, 256, 0, stream>>>(scene, 3, 8192, 4096, idx1);
    mlp_kernel<6, 16, true><<<dim3(256, B), 256, 0, stream>>>(
        scene, 3, 8192, idx1, w1_1, b1_1, w2_1, b2_1, out1, 4096);

    // Level 2: 4096 -> 2048, cin=16, F=32
    fps_kernel<16><<<B, 256, 0, stream>>>(out1, 16, 4096, 2048, idx2);
    mlp_kernel<16, 32, false><<<dim3(256, B), 256, 0, stream>>>(
        out1, 16, 4096, idx2, w1_2, b1_2, w2_2, b2_2, out2, 2048);

    // Level 3: 2048 -> 1024, cin=32, F=64
    fps_kernel<8><<<B, 256, 0, stream>>>(out2, 32, 2048, 1024, idx3);
    mlp_kernel<32, 64, false><<<dim3(256, B), 256, 0, stream>>>(
        out2, 32, 2048, idx3, w1_3, b1_3, w2_3, b2_3, out3, 1024);

    // Level 4: 1024 -> 512, cin=64, F=128
    fps_kernel<4><<<B, 256, 0, stream>>>(out3, 64, 1024, 512, idx4);
    mlp_kernel<64, 128, false><<<dim3(256, B), 256, 0, stream>>>(
        out3, 64, 1024, idx4, w1_4, b1_4, w2_4, b2_4, out4, 512);
}

// Round 4
// 11607.889 us; speedup vs baseline: 1.3113x; 1.0292x over previous
//
#include <hip/hip_runtime.h>
#include <hip/hip_bf16.h>

// ---------------------------------------------------------------------------
// Strict f64 squared distance matching numpy float64:
//   d = ((dx*dx + dy*dy) + dz*dz), every op individually rounded, no FMA.
// Coords are exact f32 values upcast to f64 (exact).
// ---------------------------------------------------------------------------
__device__ __forceinline__ double dist2d(float x, float y, float z,
                                         double px, double py, double pz) {
    double dx = __dsub_rn((double)x, px);
    double dy = __dsub_rn((double)y, py);
    double dz = __dsub_rn((double)z, pz);
    double a  = __dmul_rn(dx, dx);
    double b  = __dmul_rn(dy, dy);
    double c  = __dmul_rn(dz, dz);
    return __dadd_rn(__dadd_rn(a, b), c);
}

__device__ __forceinline__ double shfl_xor_f64(double v, int m) {
    long long bits = __double_as_longlong(v);
    int lo = __shfl_xor((int)(bits & 0xFFFFFFFFLL), m, 64);
    int hi = __shfl_xor((int)(((unsigned long long)bits) >> 32), m, 64);
    return __longlong_as_double(((long long)(unsigned)hi << 32) | (unsigned)lo);
}

__device__ __forceinline__ float readlane_f32(float v, int l) {
    return __int_as_float(__builtin_amdgcn_readlane(__float_as_int(v), l));
}

__device__ __forceinline__ double readfirstlane_f64(double v) {
    long long b = __double_as_longlong(v);
    int lo = __builtin_amdgcn_readfirstlane((int)(b & 0xFFFFFFFFLL));
    int hi = __builtin_amdgcn_readfirstlane((int)(((unsigned long long)b) >> 32));
    return __longlong_as_double(((long long)(unsigned)hi << 32) | (unsigned)lo);
}

// ---------------------------------------------------------------------------
// FPS: one block (512 threads = 8 waves) per batch. Point p = j*512 + tid.
// State in registers: f32 coords (exact), f64 running min-dist (bit-matches
// the numpy float64 reference), f32 screen threshold.
// Per iteration:
//   - wave butterfly max on f64 best (value only, 2 shfls/step), winner's
//     (idx,x,y,z) recovered via ballot + readlane (VALU, no extra DS),
//     exact ties (duplicate distances) resolved by min-index slow path
//   - 8 wave partials in LDS (double-buffered, ONE barrier/iter), 3-step
//     cross-wave reduce, winner coords ride the partials (no global q-load)
//   - fused update+scan: f32 screen (margin 4e-6 >> 1e-6 error bound) gates
//     a wave-uniform exact-f64 fmin path; skipped updates are provably
//     no-ops, so mind64 stays bit-exact; next iteration's argmax tracked
//     in the same loop.
// ---------------------------------------------------------------------------
template <int PPT>
__global__ __launch_bounds__(512, 2) void fps_kernel(
    const float* __restrict__ pts,  // [B][n_in][stride], xyz at channels 0..2
    int stride, int npoints,
    int* __restrict__ idx_out)      // [B][npoints]
{
    const int batch = blockIdx.x;
    const int tid   = threadIdx.x;
    const int lane  = tid & 63;
    const int wv    = tid >> 6;
    const int n_in  = PPT * 512;

    const float* base = pts + (size_t)batch * n_in * stride;
    int* iout = idx_out + (size_t)batch * npoints;

    __shared__ double s_m[2][8];
    __shared__ int    s_i[2][8];
    __shared__ float  s_x[2][8], s_y[2][8], s_z[2][8];

    float  cx[PPT], cy[PPT], cz[PPT];
    double md[PPT];
    float  th[PPT];

#pragma unroll
    for (int j = 0; j < PPT; ++j) {
        int p = j * 512 + tid;
        const float* r = base + (size_t)p * stride;
        cx[j] = r[0]; cy[j] = r[1]; cz[j] = r[2];
    }

    // first selected point is index 0
    float q0x = base[0], q0y = base[1], q0z = base[2];
    if (tid == 0) iout[0] = 0;

    // init mind + fused scan for the first selection
    double bv = -1.0;
    int    bi = 0x7FFFFFFF;
    float  bx = 0.f, by = 0.f, bz = 0.f;
#pragma unroll
    for (int j = 0; j < PPT; ++j) {
        md[j] = dist2d(cx[j], cy[j], cz[j], (double)q0x, (double)q0y, (double)q0z);
        th[j] = __fmul_rn((float)md[j], 1.000004f);
        if (md[j] > bv) { bv = md[j]; bi = j * 512 + tid; bx = cx[j]; by = cy[j]; bz = cz[j]; }
    }

    for (int i = 1; i < npoints; ++i) {
        const int par = i & 1;

        // ---- wave-level max on value only ----
        double red = bv;
#pragma unroll
        for (int mm = 32; mm >= 1; mm >>= 1) {
            double ov = shfl_xor_f64(red, mm);
            if (ov > red) red = ov;
        }
        // recover winner lane (tie -> min original index, exact)
        unsigned long long cmask = __ballot(bv == red);
        int wl;
        if (__popcll(cmask) > 1) {
            int mi = 0x7FFFFFFF, ml = 0;
            unsigned long long t2 = cmask;
            while (t2) {
                int l  = __ffsll((unsigned long long)t2) - 1;
                int ci = __builtin_amdgcn_readlane(bi, l);
                if (ci < mi) { mi = ci; ml = l; }
                t2 &= t2 - 1;
            }
            wl = ml;
        } else {
            wl = __ffsll((unsigned long long)cmask) - 1;
        }
        int   wi = __builtin_amdgcn_readlane(bi, wl);
        float wx = readlane_f32(bx, wl);
        float wy = readlane_f32(by, wl);
        float wz = readlane_f32(bz, wl);
        if (lane == 0) {
            s_m[par][wv] = red; s_i[par][wv] = wi;
            s_x[par][wv] = wx;  s_y[par][wv] = wy; s_z[par][wv] = wz;
        }
        __syncthreads();

        // ---- cross-wave reduce of the 8 partials (lanes 0..7 active) ----
        const int sl = lane & 7;
        double pm = s_m[par][sl];
        double v2 = (lane < 8) ? pm : -2.0;
#pragma unroll
        for (int mm = 4; mm >= 1; mm >>= 1) {
            double ov = shfl_xor_f64(v2, mm);
            if (ov > v2) v2 = ov;
        }
        double vm2 = readfirstlane_f64(v2);
        unsigned long long c2 = __ballot((lane < 8) && (pm == vm2));
        int wl2;
        if (__popcll(c2) > 1) {
            int mi = 0x7FFFFFFF, ml = 0;
            unsigned long long t2 = c2;
            while (t2) {
                int l  = __ffsll((unsigned long long)t2) - 1;
                int ci = __builtin_amdgcn_readlane(s_i[par][sl], l);
                if (ci < mi) { mi = ci; ml = l; }
                t2 &= t2 - 1;
            }
            wl2 = ml;
        } else {
            wl2 = __ffsll((unsigned long long)c2) - 1;
        }
        int   best = __builtin_amdgcn_readlane(s_i[par][sl], wl2);
        float qx   = readlane_f32(s_x[par][sl], wl2);
        float qy   = readlane_f32(s_y[par][sl], wl2);
        float qz   = readlane_f32(s_z[par][sl], wl2);
        if (tid == 0) iout[i] = best;

        const double qx64 = (double)qx, qy64 = (double)qy, qz64 = (double)qz;

        // ---- fused screen + exact update + next-iteration scan ----
        bv = -1.0; bi = 0x7FFFFFFF;
#pragma unroll
        for (int j = 0; j < PPT; ++j) {
            float dx = __fsub_rn(cx[j], qx);
            float dy = __fsub_rn(cy[j], qy);
            float dz = __fsub_rn(cz[j], qz);
            float d32 = __fadd_rn(__fadd_rn(__fmul_rn(dx, dx), __fmul_rn(dy, dy)),
                                  __fmul_rn(dz, dz));
            if (__any(d32 < th[j])) {
                double d = dist2d(cx[j], cy[j], cz[j], qx64, qy64, qz64);
                md[j] = fmin(md[j], d);
                th[j] = __fmul_rn((float)md[j], 1.000004f);
            }
            if (md[j] > bv) { bv = md[j]; bi = j * 512 + tid; bx = cx[j]; by = cy[j]; bz = cz[j]; }
        }
    }
}

// ---------------------------------------------------------------------------
// Gather + 2-layer pointwise MLP + xyz/feat concat, one kernel per level.
// Block: 256 threads = P points x F channels. LDS stages the gathered row
// (xs) and hidden activations (h); all LDS reads are same-address broadcasts
// within a point group -> conflict-free.
// out[., c] = c < 3 ? gathered_xyz[c] : feat[c]
// ---------------------------------------------------------------------------
template <int CIN, int F, bool REPEAT>
__global__ __launch_bounds__(256) void mlp_kernel(
    const float* __restrict__ pts, int stride, int n_in,
    const int* __restrict__ idx,
    const float* __restrict__ w1, const float* __restrict__ b1,
    const float* __restrict__ w2, const float* __restrict__ b2,
    float* __restrict__ out, int np)
{
    constexpr int P    = 256 / F;
    constexpr int CINS = REPEAT ? (CIN / 2) : CIN;  // stored input channels
    constexpr int LOGF = (F == 16) ? 4 : (F == 32) ? 5 : (F == 64) ? 6 : 7;

    __shared__ float xs[P][CINS];
    __shared__ float h[P][F];

    const int tid = threadIdx.x;
    const int pl  = tid >> LOGF;       // point within block
    const int c   = tid & (F - 1);     // output channel
    const int b   = blockIdx.y;
    const int pid = blockIdx.x * P + pl;

    const int id = idx[(size_t)b * np + pid];
    const float* row = pts + ((size_t)b * n_in + id) * stride;

    if (c < CINS) xs[pl][c] = row[c];
    __syncthreads();

    // h = relu(x @ w1 + b1)
    float acc = b1[c];
#pragma unroll
    for (int k = 0; k < CIN; ++k) {
        const int xk = REPEAT ? (k % 3) : k;
        acc = fmaf(xs[pl][xk], w1[k * F + c], acc);
    }
    h[pl][c] = fmaxf(acc, 0.0f);
    __syncthreads();

    // feat = h @ w2 + b2
    float acc2 = b2[c];
#pragma unroll
    for (int f = 0; f < F; ++f)
        acc2 = fmaf(h[pl][f], w2[f * F + c], acc2);

    float res = (c < 3) ? xs[pl][c] : acc2;
    out[((size_t)b * np + pid) * (size_t)F + c] = res;
}

// ---------------------------------------------------------------------------
// Launch
// ---------------------------------------------------------------------------
extern "C" void kernel_launch(void* const* d_in, const int* in_sizes, int n_in_cnt,
                              void* d_out, int out_size, void* d_ws, size_t ws_size,
                              hipStream_t stream) {
    const float* scene = (const float*)d_in[0];
    const float* w1_1 = (const float*)d_in[1];
    const float* b1_1 = (const float*)d_in[2];
    const float* w2_1 = (const float*)d_in[3];
    const float* b2_1 = (const float*)d_in[4];
    const float* w1_2 = (const float*)d_in[5];
    const float* b1_2 = (const float*)d_in[6];
    const float* w2_2 = (const float*)d_in[7];
    const float* b2_2 = (const float*)d_in[8];
    const float* w1_3 = (const float*)d_in[9];
    const float* b1_3 = (const float*)d_in[10];
    const float* w2_3 = (const float*)d_in[11];
    const float* b2_3 = (const float*)d_in[12];
    const float* w1_4 = (const float*)d_in[13];
    const float* b1_4 = (const float*)d_in[14];
    const float* w2_4 = (const float*)d_in[15];
    const float* b2_4 = (const float*)d_in[16];

    float* out  = (float*)d_out;
    float* out1 = out;                 // [8][4096][16]
    float* out2 = out + 524288;        // [8][2048][32]
    float* out3 = out + 1048576;       // [8][1024][64]
    float* out4 = out + 1572864;       // [8][512][128]

    int* idx1 = (int*)d_ws;            // 8*4096
    int* idx2 = idx1 + 8 * 4096;       // 8*2048
    int* idx3 = idx2 + 8 * 2048;       // 8*1024
    int* idx4 = idx3 + 8 * 1024;       // 8*512

    const int B = 8;

    // Level 1: N=8192 -> 4096, cin=6 (repeat), F=16
    fps_kernel<16><<<B, 512, 0, stream>>>(scene, 3, 4096, idx1);
    mlp_kernel<6, 16, true><<<dim3(256, B), 256, 0, stream>>>(
        scene, 3, 8192, idx1, w1_1, b1_1, w2_1, b2_1, out1, 4096);

    // Level 2: 4096 -> 2048, cin=16, F=32
    fps_kernel<8><<<B, 512, 0, stream>>>(out1, 16, 2048, idx2);
    mlp_kernel<16, 32, false><<<dim3(256, B), 256, 0, stream>>>(
        out1, 16, 4096, idx2, w1_2, b1_2, w2_2, b2_2, out2, 2048);

    // Level 3: 2048 -> 1024, cin=32, F=64
    fps_kernel<4><<<B, 512, 0, stream>>>(out2, 32, 1024, idx3);
    mlp_kernel<32, 64, false><<<dim3(256, B), 256, 0, stream>>>(
        out2, 32, 2048, idx3, w1_3, b1_3, w2_3, b2_3, out3, 1024);

    // Level 4: 1024 -> 512, cin=64, F=128
    fps_kernel<2><<<B, 512, 0, stream>>>(out3, 64, 512, idx4);
    mlp_kernel<64, 128, false><<<dim3(256, B), 256, 0, stream>>>(
        out3, 64, 1024, idx4, w1_4, b1_4, w2_4, b2_4, out4, 512);
}

// Round 5
// 8457.809 us; speedup vs baseline: 1.7997x; 1.3724x over previous
//
#include <hip/hip_runtime.h>
#include <hip/hip_bf16.h>

// ---------------------------------------------------------------------------
// Strict f64 squared distance matching numpy float64:
//   d = ((dx*dx + dy*dy) + dz*dz), every op individually rounded, no FMA.
// Coords are exact f32 values upcast to f64 (exact).
// ---------------------------------------------------------------------------
__device__ __forceinline__ double dist2d(float x, float y, float z,
                                         double px, double py, double pz) {
    double dx = __dsub_rn((double)x, px);
    double dy = __dsub_rn((double)y, py);
    double dz = __dsub_rn((double)z, pz);
    double a  = __dmul_rn(dx, dx);
    double b  = __dmul_rn(dy, dy);
    double c  = __dmul_rn(dz, dz);
    return __dadd_rn(__dadd_rn(a, b), c);
}

// DPP move where lanes with invalid source keep their own value
// (old == src, bound_ctrl = false). Pure VALU, no DS pipe.
template <int CTRL>
__device__ __forceinline__ double dpp_f64_keep(double v) {
    long long b = __double_as_longlong(v);
    int lo = (int)(b & 0xFFFFFFFFLL);
    int hi = (int)(((unsigned long long)b) >> 32);
    int lo2 = __builtin_amdgcn_update_dpp(lo, lo, CTRL, 0xF, 0xF, false);
    int hi2 = __builtin_amdgcn_update_dpp(hi, hi, CTRL, 0xF, 0xF, false);
    return __longlong_as_double(((long long)(unsigned)hi2 << 32) | (unsigned)lo2);
}

// After this, lane 63 holds max over all 64 lanes.
__device__ __forceinline__ double wave_max_f64(double v) {
    v = fmax(v, dpp_f64_keep<0x111>(v));  // row_shr:1
    v = fmax(v, dpp_f64_keep<0x112>(v));  // row_shr:2
    v = fmax(v, dpp_f64_keep<0x114>(v));  // row_shr:4
    v = fmax(v, dpp_f64_keep<0x118>(v));  // row_shr:8
    v = fmax(v, dpp_f64_keep<0x142>(v));  // row_bcast:15
    v = fmax(v, dpp_f64_keep<0x143>(v));  // row_bcast:31
    return v;
}

__device__ __forceinline__ double readlane_f64(double v, int l) {
    long long b = __double_as_longlong(v);
    int lo = __builtin_amdgcn_readlane((int)(b & 0xFFFFFFFFLL), l);
    int hi = __builtin_amdgcn_readlane((int)(((unsigned long long)b) >> 32), l);
    return __longlong_as_double(((long long)(unsigned)hi << 32) | (unsigned)lo);
}

// ---------------------------------------------------------------------------
// FPS: one block (512 threads = 8 waves) per batch. Point p = j*512 + tid.
// f32 coords in registers (exact); f64 running min-dist (bit-matches numpy
// float64); f32 screen thresholds.
// Per iteration:
//   - DPP-based wave max on the f64 value only (~120 cyc, no DS pipe);
//     winner lane via ballot (popc==1 fast path; exact min-index slow path
//     for ties), winner index via one readlane; lane0 writes (max, idx) to
//     double-buffered LDS partials; ONE barrier.
//   - cross-wave: all waves read the 8 partials (lanes 0-7), 3 DPP steps,
//     ballot again -> global best index.
//   - winner coords via same-address broadcast global load (L2-hot).
//   - update loop: per-j wave-uniform f32 screen gates BOTH the exact-f64
//     fmin update AND the f64 rescan. Screen-skipped updates are provably
//     no-ops (margin 1.000004 >> f32 relative error bound), so md stays
//     bit-exact; if no slot in the wave changed, the previous per-lane
//     (bv,bi) argmax state is still valid and the f64 scan is skipped.
// ---------------------------------------------------------------------------
template <int PPT>
__global__ __launch_bounds__(512, 2) void fps_kernel(
    const float* __restrict__ pts,  // [B][n_in][stride], xyz at channels 0..2
    int stride, int npoints,
    int* __restrict__ idx_out)      // [B][npoints]
{
    const int batch = blockIdx.x;
    const int tid   = threadIdx.x;
    const int lane  = tid & 63;
    const int wv    = tid >> 6;
    const int n_in  = PPT * 512;

    const float* base = pts + (size_t)batch * n_in * stride;
    int* iout = idx_out + (size_t)batch * npoints;

    __shared__ double s_m[2][8];
    __shared__ int    s_i[2][8];

    float  cx[PPT], cy[PPT], cz[PPT];
    double md[PPT];
    float  th[PPT];

#pragma unroll
    for (int j = 0; j < PPT; ++j) {
        int p = j * 512 + tid;
        const float* r = base + (size_t)p * stride;
        cx[j] = r[0]; cy[j] = r[1]; cz[j] = r[2];
    }

    // first selected point is index 0
    float q0x = base[0], q0y = base[1], q0z = base[2];
    if (tid == 0) iout[0] = 0;

    double bv = -1.0;
    int    bi = 0x7FFFFFFF;
#pragma unroll
    for (int j = 0; j < PPT; ++j) {
        md[j] = dist2d(cx[j], cy[j], cz[j], (double)q0x, (double)q0y, (double)q0z);
        th[j] = __fmul_rn((float)md[j], 1.000004f);
        if (md[j] > bv) { bv = md[j]; bi = j * 512 + tid; }
    }

    for (int i = 1; i < npoints; ++i) {
        const int par = i & 1;

        // ---- wave-level max (value only, DPP) ----
        double wmax = readlane_f64(wave_max_f64(bv), 63);
        unsigned long long cm = __ballot(bv == wmax);
        int wl;
        if (__popcll(cm) == 1) {
            wl = __ffsll(cm) - 1;
        } else {  // exact tie: pick lane holding the min index (rare)
            int mi = 0x7FFFFFFF, ml = 0;
            unsigned long long t2 = cm;
            while (t2) {
                int l  = __ffsll(t2) - 1;
                int ci = __builtin_amdgcn_readlane(bi, l);
                if (ci < mi) { mi = ci; ml = l; }
                t2 &= t2 - 1;
            }
            wl = ml;
        }
        int wi = __builtin_amdgcn_readlane(bi, wl);
        if (lane == 0) { s_m[par][wv] = wmax; s_i[par][wv] = wi; }
        __syncthreads();

        // ---- cross-wave reduce of 8 partials (lanes 0..7 live) ----
        double pm   = s_m[par][lane & 7];
        int    pidx = s_i[par][lane & 7];
        double v2 = (lane < 8) ? pm : -1.0;
        v2 = fmax(v2, dpp_f64_keep<0x111>(v2));
        v2 = fmax(v2, dpp_f64_keep<0x112>(v2));
        v2 = fmax(v2, dpp_f64_keep<0x114>(v2));
        double gmax = readlane_f64(v2, 7);
        unsigned long long c2 = __ballot((lane < 8) && (pm == gmax));
        int wl2;
        if (__popcll(c2) == 1) {
            wl2 = __ffsll(c2) - 1;
        } else {
            int mi = 0x7FFFFFFF, ml = 0;
            unsigned long long t2 = c2;
            while (t2) {
                int l  = __ffsll(t2) - 1;
                int ci = __builtin_amdgcn_readlane(pidx, l);
                if (ci < mi) { mi = ci; ml = l; }
                t2 &= t2 - 1;
            }
            wl2 = ml;
        }
        int best = __builtin_amdgcn_readlane(pidx, wl2);
        if (tid == 0) iout[i] = best;

        // winner coords: same-address broadcast load, L2-hot
        const float* rb = base + (size_t)best * stride;
        float qx = rb[0], qy = rb[1], qz = rb[2];
        const double qx64 = (double)qx, qy64 = (double)qy, qz64 = (double)qz;

        // ---- screened update; f64 only where the wave might change ----
        bool changed = false;
#pragma unroll
        for (int j = 0; j < PPT; ++j) {
            float dx = __fsub_rn(cx[j], qx);
            float dy = __fsub_rn(cy[j], qy);
            float dz = __fsub_rn(cz[j], qz);
            float d32 = __fadd_rn(__fadd_rn(__fmul_rn(dx, dx), __fmul_rn(dy, dy)),
                                  __fmul_rn(dz, dz));
            if (__any(d32 < th[j])) {
                double d = dist2d(cx[j], cy[j], cz[j], qx64, qy64, qz64);
                md[j] = fmin(md[j], d);   // no-op for unflagged lanes (proven)
                th[j] = __fmul_rn((float)md[j], 1.000004f);
                changed = true;           // wave-uniform
            }
        }
        if (changed) {  // rescan only when some md in this wave moved
            bv = -1.0; bi = 0x7FFFFFFF;
#pragma unroll
            for (int j = 0; j < PPT; ++j)
                if (md[j] > bv) { bv = md[j]; bi = j * 512 + tid; }
        }
    }
}

// ---------------------------------------------------------------------------
// Gather + 2-layer pointwise MLP + xyz/feat concat, one kernel per level.
// ---------------------------------------------------------------------------
template <int CIN, int F, bool REPEAT>
__global__ __launch_bounds__(256) void mlp_kernel(
    const float* __restrict__ pts, int stride, int n_in,
    const int* __restrict__ idx,
    const float* __restrict__ w1, const float* __restrict__ b1,
    const float* __restrict__ w2, const float* __restrict__ b2,
    float* __restrict__ out, int np)
{
    constexpr int P    = 256 / F;
    constexpr int CINS = REPEAT ? (CIN / 2) : CIN;  // stored input channels
    constexpr int LOGF = (F == 16) ? 4 : (F == 32) ? 5 : (F == 64) ? 6 : 7;

    __shared__ float xs[P][CINS];
    __shared__ float h[P][F];

    const int tid = threadIdx.x;
    const int pl  = tid >> LOGF;       // point within block
    const int c   = tid & (F - 1);     // output channel
    const int b   = blockIdx.y;
    const int pid = blockIdx.x * P + pl;

    const int id = idx[(size_t)b * np + pid];
    const float* row = pts + ((size_t)b * n_in + id) * stride;

    if (c < CINS) xs[pl][c] = row[c];
    __syncthreads();

    float acc = b1[c];
#pragma unroll
    for (int k = 0; k < CIN; ++k) {
        const int xk = REPEAT ? (k % 3) : k;
        acc = fmaf(xs[pl][xk], w1[k * F + c], acc);
    }
    h[pl][c] = fmaxf(acc, 0.0f);
    __syncthreads();

    float acc2 = b2[c];
#pragma unroll
    for (int f = 0; f < F; ++f)
        acc2 = fmaf(h[pl][f], w2[f * F + c], acc2);

    float res = (c < 3) ? xs[pl][c] : acc2;
    out[((size_t)b * np + pid) * (size_t)F + c] = res;
}

// ---------------------------------------------------------------------------
// Launch
// ---------------------------------------------------------------------------
extern "C" void kernel_launch(void* const* d_in, const int* in_sizes, int n_in_cnt,
                              void* d_out, int out_size, void* d_ws, size_t ws_size,
                              hipStream_t stream) {
    const float* scene = (const float*)d_in[0];
    const float* w1_1 = (const float*)d_in[1];
    const float* b1_1 = (const float*)d_in[2];
    const float* w2_1 = (const float*)d_in[3];
    const float* b2_1 = (const float*)d_in[4];
    const float* w1_2 = (const float*)d_in[5];
    const float* b1_2 = (const float*)d_in[6];
    const float* w2_2 = (const float*)d_in[7];
    const float* b2_2 = (const float*)d_in[8];
    const float* w1_3 = (const float*)d_in[9];
    const float* b1_3 = (const float*)d_in[10];
    const float* w2_3 = (const float*)d_in[11];
    const float* b2_3 = (const float*)d_in[12];
    const float* w1_4 = (const float*)d_in[13];
    const float* b1_4 = (const float*)d_in[14];
    const float* w2_4 = (const float*)d_in[15];
    const float* b2_4 = (const float*)d_in[16];

    float* out  = (float*)d_out;
    float* out1 = out;                 // [8][4096][16]
    float* out2 = out + 524288;        // [8][2048][32]
    float* out3 = out + 1048576;       // [8][1024][64]
    float* out4 = out + 1572864;       // [8][512][128]

    int* idx1 = (int*)d_ws;            // 8*4096
    int* idx2 = idx1 + 8 * 4096;       // 8*2048
    int* idx3 = idx2 + 8 * 2048;       // 8*1024
    int* idx4 = idx3 + 8 * 1024;       // 8*512

    const int B = 8;

    // Level 1: N=8192 -> 4096, cin=6 (repeat), F=16
    fps_kernel<16><<<B, 512, 0, stream>>>(scene, 3, 4096, idx1);
    mlp_kernel<6, 16, true><<<dim3(256, B), 256, 0, stream>>>(
        scene, 3, 8192, idx1, w1_1, b1_1, w2_1, b2_1, out1, 4096);

    // Level 2: 4096 -> 2048, cin=16, F=32
    fps_kernel<8><<<B, 512, 0, stream>>>(out1, 16, 2048, idx2);
    mlp_kernel<16, 32, false><<<dim3(256, B), 256, 0, stream>>>(
        out1, 16, 4096, idx2, w1_2, b1_2, w2_2, b2_2, out2, 2048);

    // Level 3: 2048 -> 1024, cin=32, F=64
    fps_kernel<4><<<B, 512, 0, stream>>>(out2, 32, 1024, idx3);
    mlp_kernel<32, 64, false><<<dim3(256, B), 256, 0, stream>>>(
        out2, 32, 2048, idx3, w1_3, b1_3, w2_3, b2_3, out3, 1024);

    // Level 4: 1024 -> 512, cin=64, F=128
    fps_kernel<2><<<B, 512, 0, stream>>>(out3, 64, 512, idx4);
    mlp_kernel<64, 128, false><<<dim3(256, B), 256, 0, stream>>>(
        out3, 64, 1024, idx4, w1_4, b1_4, w2_4, b2_4, out4, 512);
}

// Round 6
// 8406.223 us; speedup vs baseline: 1.8108x; 1.0061x over previous
//
#include <hip/hip_runtime.h>
#include <hip/hip_bf16.h>

// ---------------------------------------------------------------------------
// Strict f64 squared distance matching numpy float64:
//   d = ((dx*dx + dy*dy) + dz*dz), every op individually rounded, no FMA.
// Coords are exact f32 values upcast to f64 (exact).
// ---------------------------------------------------------------------------
__device__ __forceinline__ double dist2d(float x, float y, float z,
                                         double px, double py, double pz) {
    double dx = __dsub_rn((double)x, px);
    double dy = __dsub_rn((double)y, py);
    double dz = __dsub_rn((double)z, pz);
    double a  = __dmul_rn(dx, dx);
    double b  = __dmul_rn(dy, dy);
    double c  = __dmul_rn(dz, dz);
    return __dadd_rn(__dadd_rn(a, b), c);
}

// DPP move; lanes with invalid source keep their own value (bound_ctrl=false).
template <int CTRL>
__device__ __forceinline__ double dpp_f64_keep(double v) {
    long long b = __double_as_longlong(v);
    int lo = (int)(b & 0xFFFFFFFFLL);
    int hi = (int)(((unsigned long long)b) >> 32);
    int lo2 = __builtin_amdgcn_update_dpp(lo, lo, CTRL, 0xF, 0xF, false);
    int hi2 = __builtin_amdgcn_update_dpp(hi, hi, CTRL, 0xF, 0xF, false);
    return __longlong_as_double(((long long)(unsigned)hi2 << 32) | (unsigned)lo2);
}

// After this, lane 63 holds max over all 64 lanes.
__device__ __forceinline__ double wave_max_f64(double v) {
    v = fmax(v, dpp_f64_keep<0x111>(v));  // row_shr:1
    v = fmax(v, dpp_f64_keep<0x112>(v));  // row_shr:2
    v = fmax(v, dpp_f64_keep<0x114>(v));  // row_shr:4
    v = fmax(v, dpp_f64_keep<0x118>(v));  // row_shr:8
    v = fmax(v, dpp_f64_keep<0x142>(v));  // row_bcast:15
    v = fmax(v, dpp_f64_keep<0x143>(v));  // row_bcast:31
    return v;
}

__device__ __forceinline__ double readlane_f64(double v, int l) {
    long long b = __double_as_longlong(v);
    int lo = __builtin_amdgcn_readlane((int)(b & 0xFFFFFFFFLL), l);
    int hi = __builtin_amdgcn_readlane((int)(((unsigned long long)b) >> 32), l);
    return __longlong_as_double(((long long)(unsigned)hi << 32) | (unsigned)lo);
}

// ---------------------------------------------------------------------------
// FPS. One block per batch. Point p = j*NT + tid, j < PPT, n_in = PPT*NT.
// f32 coords in registers (exact); f64 running min-dist (bit-matches numpy
// float64); f32 screen thresholds.
//   - DPP wave max (value only) + ballot winner recovery (exact min-index
//     tie slow path); lane0 writes (max, idx) to double-buffered partials;
//     ONE barrier/iter; cross-wave DPP reduce of NWAVES partials.
//   - winner coords from an LDS xyz mirror (MIRROR=true; broadcast ds_read)
//     or a clamped same-address global load (L1, mirror doesn't fit 64KB).
//   - update: branchless per-slot f32 fma screen accumulated into a
//     wave-uniform fmask; ONE branch guards the whole f64-update + rescan
//     block. Screen margin 1.000004 >> 3-ulp fma error, so screened-out
//     slots are provably unchanged; md stays bit-exact.
// ---------------------------------------------------------------------------
template <int PPT, int NT, bool MIRROR>
__global__ __launch_bounds__(NT, 2) void fps_kernel(
    const float* __restrict__ pts,  // [B][n_in][stride], xyz at channels 0..2
    int stride, int npoints,
    int* __restrict__ idx_out)      // [B][npoints]
{
    constexpr int NWAVES = NT / 64;
    constexpr int N_IN   = PPT * NT;

    const int batch = blockIdx.x;
    const int tid   = threadIdx.x;
    const int lane  = tid & 63;
    const int wv    = tid >> 6;

    const float* base = pts + (size_t)batch * N_IN * stride;
    int* iout = idx_out + (size_t)batch * npoints;

    __shared__ double s_m[2][NWAVES];
    __shared__ int    s_i[2][NWAVES];
    __shared__ float  s_pts[MIRROR ? N_IN * 3 : 4];

    float  cx[PPT], cy[PPT], cz[PPT];
    double md[PPT];
    float  th[PPT];

#pragma unroll
    for (int j = 0; j < PPT; ++j) {
        int p = j * NT + tid;
        const float* r = base + (size_t)p * stride;
        cx[j] = r[0]; cy[j] = r[1]; cz[j] = r[2];
        if (MIRROR) {
            s_pts[p * 3 + 0] = cx[j];
            s_pts[p * 3 + 1] = cy[j];
            s_pts[p * 3 + 2] = cz[j];
        }
    }

    // first selected point is index 0
    float q0x = base[0], q0y = base[1], q0z = base[2];
    if (tid == 0) iout[0] = 0;

    double bv = -1.0;
    int    bi = 0x7FFFFFFF;
#pragma unroll
    for (int j = 0; j < PPT; ++j) {
        md[j] = dist2d(cx[j], cy[j], cz[j], (double)q0x, (double)q0y, (double)q0z);
        th[j] = __fmul_rn((float)md[j], 1.000004f);
        if (md[j] > bv) { bv = md[j]; bi = j * NT + tid; }
    }

    for (int i = 1; i < npoints; ++i) {
        const int par = i & 1;

        // ---- wave-level max (value only, DPP) ----
        double wmax = readlane_f64(wave_max_f64(bv), 63);
        unsigned long long cm = __ballot(bv == wmax);
        int wl;
        if (__popcll(cm) == 1) {
            wl = __ffsll(cm) - 1;
        } else {  // exact tie: pick lane holding the min index (rare)
            int mi = 0x7FFFFFFF, ml = 0;
            unsigned long long t2 = cm;
            while (t2) {
                int l  = __ffsll(t2) - 1;
                int ci = __builtin_amdgcn_readlane(bi, l);
                if (ci < mi) { mi = ci; ml = l; }
                t2 &= t2 - 1;
            }
            wl = ml;
        }
        int wi = __builtin_amdgcn_readlane(bi, wl);
        if (lane == 0) { s_m[par][wv] = wmax; s_i[par][wv] = wi; }
        __syncthreads();

        // ---- cross-wave reduce of NWAVES partials (lanes 0..NWAVES-1) ----
        double pm   = s_m[par][lane & (NWAVES - 1)];
        int    pidx = s_i[par][lane & (NWAVES - 1)];
        double v2 = (lane < NWAVES) ? pm : -1.0;
        v2 = fmax(v2, dpp_f64_keep<0x111>(v2));
        v2 = fmax(v2, dpp_f64_keep<0x112>(v2));
        if (NWAVES == 8) v2 = fmax(v2, dpp_f64_keep<0x114>(v2));
        double gmax = readlane_f64(v2, NWAVES - 1);
        unsigned long long c2 = __ballot((lane < NWAVES) && (pm == gmax));
        int wl2;
        if (__popcll(c2) == 1) {
            wl2 = __ffsll(c2) - 1;
        } else {
            int mi = 0x7FFFFFFF, ml = 0;
            unsigned long long t2 = c2;
            while (t2) {
                int l  = __ffsll(t2) - 1;
                int ci = __builtin_amdgcn_readlane(pidx, l);
                if (ci < mi) { mi = ci; ml = l; }
                t2 &= t2 - 1;
            }
            wl2 = ml;
        }
        int best = __builtin_amdgcn_readlane(pidx, wl2);
        best = min(max(best, 0), N_IN - 1);   // replay-poison safety
        if (tid == 0) iout[i] = best;

        // winner coords: LDS mirror broadcast (or clamped global broadcast)
        float qx, qy, qz;
        if (MIRROR) {
            qx = s_pts[best * 3 + 0];
            qy = s_pts[best * 3 + 1];
            qz = s_pts[best * 3 + 2];
        } else {
            const float* rb = base + (size_t)best * stride;
            qx = rb[0]; qy = rb[1]; qz = rb[2];
        }
        const double qx64 = (double)qx, qy64 = (double)qy, qz64 = (double)qz;

        // ---- branchless screen -> wave-uniform fire mask ----
        int fmask = 0;
#pragma unroll
        for (int j = 0; j < PPT; ++j) {
            float dx = cx[j] - qx;
            float dy = cy[j] - qy;
            float dz = cz[j] - qz;
            float d32 = fmaf(dx, dx, fmaf(dy, dy, dz * dz));
            fmask |= (__any(d32 < th[j]) ? (1 << j) : 0);
        }

        if (fmask) {
#pragma unroll
            for (int j = 0; j < PPT; ++j) {
                if (fmask & (1 << j)) {
                    double d = dist2d(cx[j], cy[j], cz[j], qx64, qy64, qz64);
                    md[j] = fmin(md[j], d);   // no-op for unflagged lanes
                    th[j] = __fmul_rn((float)md[j], 1.000004f);
                }
            }
            // rescan only when some md in this wave may have moved
            bv = -1.0; bi = 0x7FFFFFFF;
#pragma unroll
            for (int j = 0; j < PPT; ++j)
                if (md[j] > bv) { bv = md[j]; bi = j * NT + tid; }
        }
    }
}

// ---------------------------------------------------------------------------
// Gather + 2-layer pointwise MLP + xyz/feat concat, one kernel per level.
// ---------------------------------------------------------------------------
template <int CIN, int F, bool REPEAT>
__global__ __launch_bounds__(256) void mlp_kernel(
    const float* __restrict__ pts, int stride, int n_in,
    const int* __restrict__ idx,
    const float* __restrict__ w1, const float* __restrict__ b1,
    const float* __restrict__ w2, const float* __restrict__ b2,
    float* __restrict__ out, int np)
{
    constexpr int P    = 256 / F;
    constexpr int CINS = REPEAT ? (CIN / 2) : CIN;  // stored input channels
    constexpr int LOGF = (F == 16) ? 4 : (F == 32) ? 5 : (F == 64) ? 6 : 7;

    __shared__ float xs[P][CINS];
    __shared__ float h[P][F];

    const int tid = threadIdx.x;
    const int pl  = tid >> LOGF;       // point within block
    const int c   = tid & (F - 1);     // output channel
    const int b   = blockIdx.y;
    const int pid = blockIdx.x * P + pl;

    const int id = idx[(size_t)b * np + pid];
    const float* row = pts + ((size_t)b * n_in + id) * stride;

    if (c < CINS) xs[pl][c] = row[c];
    __syncthreads();

    float acc = b1[c];
#pragma unroll
    for (int k = 0; k < CIN; ++k) {
        const int xk = REPEAT ? (k % 3) : k;
        acc = fmaf(xs[pl][xk], w1[k * F + c], acc);
    }
    h[pl][c] = fmaxf(acc, 0.0f);
    __syncthreads();

    float acc2 = b2[c];
#pragma unroll
    for (int f = 0; f < F; ++f)
        acc2 = fmaf(h[pl][f], w2[f * F + c], acc2);

    float res = (c < 3) ? xs[pl][c] : acc2;
    out[((size_t)b * np + pid) * (size_t)F + c] = res;
}

// ---------------------------------------------------------------------------
// Launch
// ---------------------------------------------------------------------------
extern "C" void kernel_launch(void* const* d_in, const int* in_sizes, int n_in_cnt,
                              void* d_out, int out_size, void* d_ws, size_t ws_size,
                              hipStream_t stream) {
    const float* scene = (const float*)d_in[0];
    const float* w1_1 = (const float*)d_in[1];
    const float* b1_1 = (const float*)d_in[2];
    const float* w2_1 = (const float*)d_in[3];
    const float* b2_1 = (const float*)d_in[4];
    const float* w1_2 = (const float*)d_in[5];
    const float* b1_2 = (const float*)d_in[6];
    const float* w2_2 = (const float*)d_in[7];
    const float* b2_2 = (const float*)d_in[8];
    const float* w1_3 = (const float*)d_in[9];
    const float* b1_3 = (const float*)d_in[10];
    const float* w2_3 = (const float*)d_in[11];
    const float* b2_3 = (const float*)d_in[12];
    const float* w1_4 = (const float*)d_in[13];
    const float* b1_4 = (const float*)d_in[14];
    const float* w2_4 = (const float*)d_in[15];
    const float* b2_4 = (const float*)d_in[16];

    float* out  = (float*)d_out;
    float* out1 = out;                 // [8][4096][16]
    float* out2 = out + 524288;        // [8][2048][32]
    float* out3 = out + 1048576;       // [8][1024][64]
    float* out4 = out + 1572864;       // [8][512][128]

    int* idx1 = (int*)d_ws;            // 8*4096
    int* idx2 = idx1 + 8 * 4096;       // 8*2048
    int* idx3 = idx2 + 8 * 2048;       // 8*1024
    int* idx4 = idx3 + 8 * 1024;       // 8*512

    const int B = 8;

    // Level 1: N=8192 -> 4096, cin=6 (repeat), F=16  (mirror: 96KB > 64KB, off)
    fps_kernel<16, 512, false><<<B, 512, 0, stream>>>(scene, 3, 4096, idx1);
    mlp_kernel<6, 16, true><<<dim3(256, B), 256, 0, stream>>>(
        scene, 3, 8192, idx1, w1_1, b1_1, w2_1, b2_1, out1, 4096);

    // Level 2: 4096 -> 2048, cin=16, F=32  (mirror 48KB)
    fps_kernel<8, 512, true><<<B, 512, 0, stream>>>(out1, 16, 2048, idx2);
    mlp_kernel<16, 32, false><<<dim3(256, B), 256, 0, stream>>>(
        out1, 16, 4096, idx2, w1_2, b1_2, w2_2, b2_2, out2, 2048);

    // Level 3: 2048 -> 1024, cin=32, F=64  (256 thr, mirror 24KB)
    fps_kernel<8, 256, true><<<B, 256, 0, stream>>>(out2, 32, 1024, idx3);
    mlp_kernel<32, 64, false><<<dim3(256, B), 256, 0, stream>>>(
        out2, 32, 2048, idx3, w1_3, b1_3, w2_3, b2_3, out3, 1024);

    // Level 4: 1024 -> 512, cin=64, F=128  (256 thr, mirror 12KB)
    fps_kernel<4, 256, true><<<B, 256, 0, stream>>>(out3, 64, 512, idx4);
    mlp_kernel<64, 128, false><<<dim3(256, B), 256, 0, stream>>>(
        out3, 64, 1024, idx4, w1_4, b1_4, w2_4, b2_4, out4, 512);
}